// Round 1
// baseline (316.753 us; speedup 1.0000x reference)
//
#include <hip/hip_runtime.h>

#define HD  64
#define FIN 128

// ---- workspace float offsets ----
#define WS_W1T   0        // [128][64] transposed W1
#define WS_MK    8192     // [64][64]  W2T @ WkT   (folded)
#define WS_MQ    12288
#define WS_MVW   16384    //           W2T @ WvT @ diag(Wsc)
#define WS_WSK1  20480    // [64]      W2T @ (WsT @ Wsc)
#define WS_BK    20544    // [64]      bk + b2@WkT
#define WS_BQ    20608
#define WS_BVW   20672    //           (bv + b2@WvT) . Wsc
#define WS_BASE  20736    // scalar: bsc + b_gate.Wsc + b2.wsk   (pad to 20800)
#define WS_H1    20800    // [N][64] bf16 relu output (32 floats-equiv per node)
// per-node 256B record buffer follows: k u8[64] | q u8[64] | vw bf16[64]

// sigmoid quintic on clamped domain x in [-2,2], encoded s = 64*x:
// sigma ~= 0.5 + s*(C1 + C3*z + C5*z^2), z = s^2   (max err ~1.2e-3)
#define C1f  3.9026344e-3f
#define C3f  (-7.67612e-8f)
#define C5f  1.2236660e-12f

__device__ __forceinline__ unsigned bf16rne(float f) {
    unsigned u = __float_as_uint(f);
    unsigned r = ((u >> 16) & 1u) + 0x7fffu;
    return (u + r) >> 16;
}
__device__ __forceinline__ uint2 pack4(float4 v) {
    uint2 r;
    r.x = bf16rne(v.x) | (bf16rne(v.y) << 16);
    r.y = bf16rne(v.z) | (bf16rne(v.w) << 16);
    return r;
}
__device__ __forceinline__ float blo(unsigned u) { return __uint_as_float(u << 16); }
__device__ __forceinline__ float bhi(unsigned u) { return __uint_as_float(u & 0xffff0000u); }

// encode 4 floats to u8 fixed-point: clamp(round(64x)+128, 0, 255)
__device__ __forceinline__ unsigned encq(float4 v) {
    int e0 = min(max(__float2int_rn(fmaf(v.x, 64.f, 128.f)), 0), 255);
    int e1 = min(max(__float2int_rn(fmaf(v.y, 64.f, 128.f)), 0), 255);
    int e2 = min(max(__float2int_rn(fmaf(v.z, 64.f, 128.f)), 0), 255);
    int e3 = min(max(__float2int_rn(fmaf(v.w, 64.f, 128.f)), 0), 255);
    return (unsigned)e0 | ((unsigned)e1 << 8) | ((unsigned)e2 << 16) | ((unsigned)e3 << 24);
}

// 4 features: k,q u8 quads + 4 bf16 vw in (va,vb)
__device__ __forceinline__ float grp4(unsigned ku, unsigned qu, unsigned va,
                                      unsigned vb, float p) {
    #pragma unroll
    for (int i = 0; i < 4; ++i) {
        float kf = (float)((ku >> (8 * i)) & 255u);
        float qf = (float)((qu >> (8 * i)) & 255u);
        unsigned vu = (i < 2) ? va : vb;
        float vf = (i & 1) ? bhi(vu) : blo(vu);
        float xx = kf + qf;                       // encoded k+q, center 256
        xx = fminf(fmaxf(xx, 128.f), 384.f);      // clamp to x in [-2,2]
        float sv = xx - 256.f;
        float z = sv * sv;
        float w = fmaf(z, C5f, C3f);
        w = fmaf(z, w, C1f);
        p = fmaf(vf * sv, w, p);
        p = fmaf(vf, 0.5f, p);
    }
    return p;
}

// ---------------------------------------------------------------------------
// Prep (14 blocks): b0 W1T transpose; b1-12 LDS-staged folds (3 matrices x
// 4 row-quarters, conflict-free via 65-stride transpose); b13 skip fold.
// ---------------------------------------------------------------------------
__global__ void gnn_prep(const float* __restrict__ W1, const float* __restrict__ W2,
                         const float* __restrict__ b2,
                         const float* __restrict__ Wk, const float* __restrict__ bk,
                         const float* __restrict__ Wq, const float* __restrict__ bq,
                         const float* __restrict__ Wv, const float* __restrict__ bv,
                         const float* __restrict__ Wsm, const float* __restrict__ Wsc,
                         const float* __restrict__ bgate, const float* __restrict__ bsc,
                         float* __restrict__ ws) {
    __shared__ float w2s[4096];
    __shared__ float wxsT[65 * 64];    // [c][o], stride 65
    int b = blockIdx.x, t = threadIdx.x;
    if (b == 0) {                                   // W1T[j][c] = W1[c][j]
        for (int idx = t; idx < HD * FIN; idx += blockDim.x) {
            int c = idx / FIN, j = idx % FIN;
            ws[WS_W1T + j * HD + c] = W1[idx];
        }
    } else if (b <= 12) {
        int m = (b - 1) >> 2, qtr = (b - 1) & 3;
        const float* Wx = (m == 0) ? Wk : (m == 1) ? Wq : Wv;
        const float* bx = (m == 0) ? bk : (m == 1) ? bq : bv;
        int moff = (m == 0) ? WS_MK : (m == 1) ? WS_MQ : WS_MVW;
        int boff = (m == 0) ? WS_BK : (m == 1) ? WS_BQ : WS_BVW;
        for (int i = t * 4; i < 4096; i += 1024)
            *(float4*)&w2s[i] = *(const float4*)&W2[i];
        for (int idx = t; idx < 4096; idx += 256) {
            int o = idx >> 6, c = idx & 63;
            wxsT[c * 65 + o] = Wx[idx];
        }
        __syncthreads();
        for (int idx = t; idx < 1024; idx += 256) {
            int a = qtr * 16 + (idx >> 6), o = idx & 63;
            float acc = 0.f;
            for (int c = 0; c < HD; ++c) acc += w2s[c * HD + a] * wxsT[c * 65 + o];
            if (m == 2) acc *= Wsc[o];
            ws[moff + a * HD + o] = acc;
        }
        if (qtr == 0 && t < HD) {
            float acc = bx[t];
            for (int c = 0; c < HD; ++c) acc += b2[c] * wxsT[c * 65 + t];
            if (m == 2) acc *= Wsc[t];
            ws[boff + t] = acc;
        }
    } else {                                        // skip-path fold
        __shared__ float wsk[HD];
        if (t < HD) {
            float a = 0.f;
            for (int d = 0; d < HD; ++d) a += Wsm[d * HD + t] * Wsc[d];
            wsk[t] = a;
        }
        __syncthreads();
        if (t < HD) {
            float a = 0.f;
            for (int c = 0; c < HD; ++c) a += W2[c * HD + t] * wsk[c];
            ws[WS_WSK1 + t] = a;
        }
        if (t == 0) {
            float a = bsc[0];
            for (int d = 0; d < HD; ++d) a += bgate[d] * Wsc[d];
            for (int c = 0; c < HD; ++c) a += b2[c] * wsk[c];
            ws[WS_BASE] = a;
        }
    }
}

// ---------------------------------------------------------------------------
// h1 = relu(x @ W1T + b1), stored bf16.  x tile staged coalesced into padded
// LDS (row stride 132 -> conflict-free group reads).  4 nodes/lane x 4 feats.
// LDS: 33.0 + 33.8 = 66.8 KB -> 2 blocks/CU.
// ---------------------------------------------------------------------------
__global__ __launch_bounds__(256, 2) void gnn_mlp1(const float* __restrict__ x,
                                                   const float* __restrict__ b1,
                                                   const float* __restrict__ ws,
                                                   uint2* __restrict__ h1out, int N) {
    __shared__ float w[FIN * HD + HD];
    __shared__ float xs[64 * 132];
    int tid = threadIdx.x;
    for (int i = tid * 4; i < FIN * HD; i += 1024)
        *(float4*)&w[i] = *(const float4*)&ws[WS_W1T + i];
    if (tid < HD) w[FIN * HD + tid] = b1[tid];

    int nbase = blockIdx.x * 64;
    for (int i4 = tid; i4 < 2048; i4 += 256) {        // 64 nodes x 32 float4
        int nl = i4 >> 5, c4 = i4 & 31;
        int node = min(nbase + nl, N - 1);
        float4 xv = ((const float4*)x)[(size_t)node * 32 + c4];
        *(float4*)&xs[nl * 132 + c4 * 4] = xv;
    }
    __syncthreads();

    int wv = tid >> 6, l = tid & 63, g = l >> 4, f = l & 15;
    int nl0 = wv * 16 + g * 4;

    float4 bias = *(const float4*)&w[FIN * HD + 4 * f];
    float4 acc[4];
    #pragma unroll
    for (int n = 0; n < 4; ++n) acc[n] = bias;

    for (int j = 0; j < FIN; j += 4) {
        float4 xv[4];
        #pragma unroll
        for (int n = 0; n < 4; ++n) xv[n] = *(const float4*)&xs[(nl0 + n) * 132 + j];
        #pragma unroll
        for (int jj = 0; jj < 4; ++jj) {
            float4 wvv = *(const float4*)&w[(j + jj) * HD + 4 * f];
            #pragma unroll
            for (int n = 0; n < 4; ++n) {
                float xsc = ((const float*)&xv[n])[jj];
                acc[n].x += xsc * wvv.x; acc[n].y += xsc * wvv.y;
                acc[n].z += xsc * wvv.z; acc[n].w += xsc * wvv.w;
            }
        }
    }
    #pragma unroll
    for (int n = 0; n < 4; ++n) {
        int node = nbase + nl0 + n;
        if (node < N) {
            float4 r;
            r.x = fmaxf(acc[n].x, 0.f); r.y = fmaxf(acc[n].y, 0.f);
            r.z = fmaxf(acc[n].z, 0.f); r.w = fmaxf(acc[n].w, 0.f);
            h1out[(size_t)node * 16 + f] = pack4(r);
        }
    }
}

// ---------------------------------------------------------------------------
// Fused k/q/vw/score from bf16 h1 (staged in LDS, row stride 36 uints).
// Outputs one 256B record per node: k u8[64] | q u8[64] | vw bf16[64].
// score[n] = base + h1 . wsk1.  LDS: 50.2 + 9.2 = 59.4 KB -> 2 blocks/CU.
// ---------------------------------------------------------------------------
__global__ __launch_bounds__(256, 2) void gnn_kqvs(const float* __restrict__ ws,
                                                   const uint2* __restrict__ h1,
                                                   unsigned* __restrict__ nodebuf,
                                                   float* __restrict__ score, int N) {
    __shared__ float w[12544];
    __shared__ unsigned hs[64 * 36];
    const int L_MK = 0, L_MQ = 4096, L_MVW = 8192, L_WSK = 12288,
              L_BK = 12352, L_BQ = 12416, L_BVW = 12480;
    int tid = threadIdx.x;
    for (int i = tid * 4; i < 12544; i += 1024)
        *(float4*)&w[i] = *(const float4*)&ws[WS_MK + i];

    int nbase = blockIdx.x * 64;
    for (int i4 = tid; i4 < 512; i4 += 256) {         // 64 nodes x 8 uint4
        int nl = i4 >> 3, c4 = i4 & 7;
        int node = min(nbase + nl, N - 1);
        uint4 hv = ((const uint4*)h1)[(size_t)node * 8 + c4];
        *(uint4*)&hs[nl * 36 + c4 * 4] = hv;
    }
    __syncthreads();
    float base = ws[WS_BASE];

    int wv = tid >> 6, l = tid & 63, g = l >> 4, f = l & 15;
    int nl0 = wv * 16 + g * 4;

    float4 accK[4], accQ[4], accV[4];
    float sacc[4];
    float4 bK = *(const float4*)&w[L_BK + 4 * f];
    float4 bQ = *(const float4*)&w[L_BQ + 4 * f];
    float4 bV = *(const float4*)&w[L_BVW + 4 * f];
    #pragma unroll
    for (int n = 0; n < 4; ++n) { accK[n] = bK; accQ[n] = bQ; accV[n] = bV; sacc[n] = 0.f; }

    for (int a = 0; a < HD; a += 4) {
        float hf[4][4];
        #pragma unroll
        for (int n = 0; n < 4; ++n) {
            uint2 hu = *(const uint2*)&hs[(nl0 + n) * 36 + (a >> 1)];
            hf[n][0] = blo(hu.x); hf[n][1] = bhi(hu.x);
            hf[n][2] = blo(hu.y); hf[n][3] = bhi(hu.y);
        }
        #pragma unroll
        for (int aa = 0; aa < 4; ++aa) {
            float4 mk = *(const float4*)&w[L_MK + (a + aa) * HD + 4 * f];
            float4 mq = *(const float4*)&w[L_MQ + (a + aa) * HD + 4 * f];
            float4 mv = *(const float4*)&w[L_MVW + (a + aa) * HD + 4 * f];
            float wk = w[L_WSK + a + aa];
            #pragma unroll
            for (int n = 0; n < 4; ++n) {
                float s1 = hf[n][aa];
                accK[n].x += s1 * mk.x; accK[n].y += s1 * mk.y;
                accK[n].z += s1 * mk.z; accK[n].w += s1 * mk.w;
                accQ[n].x += s1 * mq.x; accQ[n].y += s1 * mq.y;
                accQ[n].z += s1 * mq.z; accQ[n].w += s1 * mq.w;
                accV[n].x += s1 * mv.x; accV[n].y += s1 * mv.y;
                accV[n].z += s1 * mv.z; accV[n].w += s1 * mv.w;
                sacc[n] += s1 * wk;
            }
        }
    }
    #pragma unroll
    for (int n = 0; n < 4; ++n) {
        int node = nbase + nl0 + n;
        if (node < N) {
            unsigned* rec = nodebuf + (size_t)node * 64;
            rec[f] = encq(accK[n]);                       // k u8
            rec[16 + f] = encq(accQ[n]);                  // q u8
            *(uint2*)&rec[32 + 2 * f] = pack4(accV[n]);   // vw bf16
            if (f == 0) score[node] = base + sacc[n];
        }
    }
}

// ---------------------------------------------------------------------------
// Edge: score[dst] += sum_t sigma(k[dst]+q[src])_t * vw[src]_t
// 4 lanes/edge, u8 k/q + bf16 vw, poly sigmoid (no trans), 1 atomic/edge.
// Per edge: 1 sector k + 3 sectors q|vw = 256 B gathered.
// ---------------------------------------------------------------------------
__global__ __launch_bounds__(256) void gnn_edge(const int* __restrict__ ei,
                                                const uint4* __restrict__ nb,
                                                float* __restrict__ score, int E) {
    int t = blockIdx.x * 256 + threadIdx.x;
    int e = t >> 2;
    if (e >= E) return;
    int f = t & 3;
    int s = ei[e];
    int d = ei[E + e];
    uint4 ku = nb[(size_t)d * 16 + f];           // 16 k-bytes
    uint4 qu = nb[(size_t)s * 16 + 4 + f];       // 16 q-bytes
    uint4 va = nb[(size_t)s * 16 + 8 + 2 * f];   // 8 vw bf16
    uint4 vb = nb[(size_t)s * 16 + 9 + 2 * f];   // 8 vw bf16
    float p = 0.f;
    p = grp4(ku.x, qu.x, va.x, va.y, p);
    p = grp4(ku.y, qu.y, va.z, va.w, p);
    p = grp4(ku.z, qu.z, vb.x, vb.y, p);
    p = grp4(ku.w, qu.w, vb.z, vb.w, p);
    p += __shfl_down(p, 2, 4);
    p += __shfl_down(p, 1, 4);
    if (f == 0) atomicAdd(&score[d], p);
}

// ---------------------------------------------------------------------------
extern "C" void kernel_launch(void* const* d_in, const int* in_sizes, int n_in,
                              void* d_out, int out_size, void* d_ws, size_t ws_size,
                              hipStream_t stream) {
    const float* x    = (const float*)d_in[0];
    const int*   ei   = (const int*)d_in[1];
    const float* W1   = (const float*)d_in[2];
    const float* b1   = (const float*)d_in[3];
    const float* W2   = (const float*)d_in[4];
    const float* b2   = (const float*)d_in[5];
    const float* Wk   = (const float*)d_in[6];
    const float* bk   = (const float*)d_in[7];
    const float* Wq   = (const float*)d_in[8];
    const float* bq   = (const float*)d_in[9];
    const float* Wv   = (const float*)d_in[10];
    const float* bv   = (const float*)d_in[11];
    const float* Wsm  = (const float*)d_in[12];
    const float* bgat = (const float*)d_in[13];
    const float* Wsc  = (const float*)d_in[14];
    const float* bsc  = (const float*)d_in[15];

    int N = in_sizes[0] / FIN;
    int E = in_sizes[1] / 2;

    float* ws   = (float*)d_ws;
    float* h1   = ws + WS_H1;                     // bf16: 32 floats-equiv/node
    float* recs = h1 + (size_t)N * 32;            // 256 B/node records
    float* score = (float*)d_out;

    int NB = (N + 63) / 64;
    gnn_prep<<<14, 256, 0, stream>>>(W1, W2, b2, Wk, bk, Wq, bq, Wv, bv,
                                     Wsm, Wsc, bgat, bsc, ws);
    gnn_mlp1<<<NB, 256, 0, stream>>>(x, b1, ws, (uint2*)h1, N);
    gnn_kqvs<<<NB, 256, 0, stream>>>(ws, (const uint2*)h1, (unsigned*)recs, score, N);
    gnn_edge<<<(E * 4 + 255) / 256, 256, 0, stream>>>(ei, (const uint4*)recs, score, E);
}

// Round 2
// 310.440 us; speedup vs baseline: 1.0203x; 1.0203x over previous
//
#include <hip/hip_runtime.h>

#define HD  64
#define FIN 128

// ---- workspace float offsets ----
#define WS_W1T   0        // [128][64] transposed W1
#define WS_MK    8192     // [64][64]  W2T @ WkT   (folded)
#define WS_MQ    12288
#define WS_MVW   16384    //           W2T @ WvT @ diag(Wsc)
#define WS_WSK1  20480    // [64]      W2T @ (WsT @ Wsc)
#define WS_BK    20544    // [64]      bk + b2@WkT
#define WS_BQ    20608
#define WS_BVW   20672    //           (bv + b2@WvT) . Wsc
#define WS_BASE  20736    // scalar: bsc + b_gate.Wsc + b2.wsk   (pad to 20800)
#define WS_H1    20800    // records start here now (h1 never hits global)
// per-node 256B record buffer: k u8[64] | q u8[64] | vw bf16[64]

// sigmoid quintic on clamped domain x in [-2,2], encoded s = 64*x:
// sigma ~= 0.5 + s*(C1 + C3*z + C5*z^2), z = s^2   (max err ~1.2e-3)
#define C1f  3.9026344e-3f
#define C3f  (-7.67612e-8f)
#define C5f  1.2236660e-12f

__device__ __forceinline__ unsigned bf16rne(float f) {
    unsigned u = __float_as_uint(f);
    unsigned r = ((u >> 16) & 1u) + 0x7fffu;
    return (u + r) >> 16;
}
__device__ __forceinline__ uint2 pack4(float4 v) {
    uint2 r;
    r.x = bf16rne(v.x) | (bf16rne(v.y) << 16);
    r.y = bf16rne(v.z) | (bf16rne(v.w) << 16);
    return r;
}
__device__ __forceinline__ float blo(unsigned u) { return __uint_as_float(u << 16); }
__device__ __forceinline__ float bhi(unsigned u) { return __uint_as_float(u & 0xffff0000u); }

// encode 4 floats to u8 fixed-point: clamp(round(64x)+128, 0, 255)
__device__ __forceinline__ unsigned encq(float4 v) {
    int e0 = min(max(__float2int_rn(fmaf(v.x, 64.f, 128.f)), 0), 255);
    int e1 = min(max(__float2int_rn(fmaf(v.y, 64.f, 128.f)), 0), 255);
    int e2 = min(max(__float2int_rn(fmaf(v.z, 64.f, 128.f)), 0), 255);
    int e3 = min(max(__float2int_rn(fmaf(v.w, 64.f, 128.f)), 0), 255);
    return (unsigned)e0 | ((unsigned)e1 << 8) | ((unsigned)e2 << 16) | ((unsigned)e3 << 24);
}

// 4 features: k,q u8 quads + 4 bf16 vw in (va,vb)
__device__ __forceinline__ float grp4(unsigned ku, unsigned qu, unsigned va,
                                      unsigned vb, float p) {
    #pragma unroll
    for (int i = 0; i < 4; ++i) {
        float kf = (float)((ku >> (8 * i)) & 255u);
        float qf = (float)((qu >> (8 * i)) & 255u);
        unsigned vu = (i < 2) ? va : vb;
        float vf = (i & 1) ? bhi(vu) : blo(vu);
        float xx = kf + qf;                       // encoded k+q, center 256
        xx = fminf(fmaxf(xx, 128.f), 384.f);      // clamp to x in [-2,2]
        float sv = xx - 256.f;
        float z = sv * sv;
        float w = fmaf(z, C5f, C3f);
        w = fmaf(z, w, C1f);
        p = fmaf(vf * sv, w, p);
        p = fmaf(vf, 0.5f, p);
    }
    return p;
}

// ---------------------------------------------------------------------------
// Prep (14 blocks): b0 W1T transpose; b1-12 LDS-staged folds (3 matrices x
// 4 row-quarters, conflict-free via 65-stride transpose); b13 skip fold.
// ---------------------------------------------------------------------------
__global__ void gnn_prep(const float* __restrict__ W1, const float* __restrict__ W2,
                         const float* __restrict__ b2,
                         const float* __restrict__ Wk, const float* __restrict__ bk,
                         const float* __restrict__ Wq, const float* __restrict__ bq,
                         const float* __restrict__ Wv, const float* __restrict__ bv,
                         const float* __restrict__ Wsm, const float* __restrict__ Wsc,
                         const float* __restrict__ bgate, const float* __restrict__ bsc,
                         float* __restrict__ ws) {
    __shared__ float w2s[4096];
    __shared__ float wxsT[65 * 64];    // [c][o], stride 65
    int b = blockIdx.x, t = threadIdx.x;
    if (b == 0) {                                   // W1T[j][c] = W1[c][j]
        for (int idx = t; idx < HD * FIN; idx += blockDim.x) {
            int c = idx / FIN, j = idx % FIN;
            ws[WS_W1T + j * HD + c] = W1[idx];
        }
    } else if (b <= 12) {
        int m = (b - 1) >> 2, qtr = (b - 1) & 3;
        const float* Wx = (m == 0) ? Wk : (m == 1) ? Wq : Wv;
        const float* bx = (m == 0) ? bk : (m == 1) ? bq : bv;
        int moff = (m == 0) ? WS_MK : (m == 1) ? WS_MQ : WS_MVW;
        int boff = (m == 0) ? WS_BK : (m == 1) ? WS_BQ : WS_BVW;
        for (int i = t * 4; i < 4096; i += 1024)
            *(float4*)&w2s[i] = *(const float4*)&W2[i];
        for (int idx = t; idx < 4096; idx += 256) {
            int o = idx >> 6, c = idx & 63;
            wxsT[c * 65 + o] = Wx[idx];
        }
        __syncthreads();
        for (int idx = t; idx < 1024; idx += 256) {
            int a = qtr * 16 + (idx >> 6), o = idx & 63;
            float acc = 0.f;
            for (int c = 0; c < HD; ++c) acc += w2s[c * HD + a] * wxsT[c * 65 + o];
            if (m == 2) acc *= Wsc[o];
            ws[moff + a * HD + o] = acc;
        }
        if (qtr == 0 && t < HD) {
            float acc = bx[t];
            for (int c = 0; c < HD; ++c) acc += b2[c] * wxsT[c * 65 + t];
            if (m == 2) acc *= Wsc[t];
            ws[boff + t] = acc;
        }
    } else {                                        // skip-path fold
        __shared__ float wsk[HD];
        if (t < HD) {
            float a = 0.f;
            for (int d = 0; d < HD; ++d) a += Wsm[d * HD + t] * Wsc[d];
            wsk[t] = a;
        }
        __syncthreads();
        if (t < HD) {
            float a = 0.f;
            for (int c = 0; c < HD; ++c) a += W2[c * HD + t] * wsk[c];
            ws[WS_WSK1 + t] = a;
        }
        if (t == 0) {
            float a = bsc[0];
            for (int d = 0; d < HD; ++d) a += bgate[d] * Wsc[d];
            for (int c = 0; c < HD; ++c) a += b2[c] * wsk[c];
            ws[WS_BASE] = a;
        }
    }
}

// ---------------------------------------------------------------------------
// Fused node kernel: h = relu(x@W1T+b1) (phase 1), then k/q/vw/score (phase 2).
// Weights stream from global (W1T 32KB, folded mats 50KB: identical for all
// blocks -> L1/L2 broadcast). Only the x tile lives in LDS (33.8KB), and its
// buffer is reused for the bf16 h tile in phase 2. 3 blocks/CU.
// h never touches global memory.
// ---------------------------------------------------------------------------
__global__ __launch_bounds__(256, 3) void gnn_node(const float* __restrict__ x,
                                                   const float* __restrict__ b1,
                                                   const float* __restrict__ ws,
                                                   unsigned* __restrict__ nodebuf,
                                                   float* __restrict__ score, int N) {
    __shared__ float xs[64 * 132];                 // 33.8KB; aliased as hs below
    unsigned* hs = (unsigned*)xs;                  // [64 nodes][36 uints] bf16 h

    int tid = threadIdx.x;
    int nbase = blockIdx.x * 64;

    // ---- stage x tile (coalesced, padded stride 132) ----
    for (int i4 = tid; i4 < 2048; i4 += 256) {     // 64 nodes x 32 float4
        int nl = i4 >> 5, c4 = i4 & 31;
        int node = min(nbase + nl, N - 1);
        float4 xv = ((const float4*)x)[(size_t)node * 32 + c4];
        *(float4*)&xs[nl * 132 + c4 * 4] = xv;
    }
    __syncthreads();

    int wv = tid >> 6, l = tid & 63, g = l >> 4, f = l & 15;
    int nl0 = wv * 16 + g * 4;

    // ---- phase 1: h = relu(x @ W1T + b1), W1T streamed from global ----
    const float* w1 = ws + WS_W1T;
    float4 bias = *(const float4*)&b1[4 * f];
    float4 acc[4];
    #pragma unroll
    for (int n = 0; n < 4; ++n) acc[n] = bias;

    for (int j = 0; j < FIN; j += 4) {
        float4 xv[4];
        #pragma unroll
        for (int n = 0; n < 4; ++n) xv[n] = *(const float4*)&xs[(nl0 + n) * 132 + j];
        #pragma unroll
        for (int jj = 0; jj < 4; ++jj) {
            float4 wvv = *(const float4*)&w1[(j + jj) * HD + 4 * f];
            #pragma unroll
            for (int n = 0; n < 4; ++n) {
                float xsc = ((const float*)&xv[n])[jj];
                acc[n].x += xsc * wvv.x; acc[n].y += xsc * wvv.y;
                acc[n].z += xsc * wvv.z; acc[n].w += xsc * wvv.w;
            }
        }
    }
    __syncthreads();                               // all reads of xs done
    #pragma unroll
    for (int n = 0; n < 4; ++n) {                  // write bf16 h into hs (alias)
        float4 r;
        r.x = fmaxf(acc[n].x, 0.f); r.y = fmaxf(acc[n].y, 0.f);
        r.z = fmaxf(acc[n].z, 0.f); r.w = fmaxf(acc[n].w, 0.f);
        *(uint2*)&hs[(nl0 + n) * 36 + 2 * f] = pack4(r);
    }
    __syncthreads();                               // hs complete

    // ---- phase 2: k/q/vw/score, folded mats streamed from global ----
    float base = ws[WS_BASE];
    float4 accK[4], accQ[4], accV[4];
    float sacc[4];
    float4 bK = *(const float4*)&ws[WS_BK + 4 * f];
    float4 bQ = *(const float4*)&ws[WS_BQ + 4 * f];
    float4 bV = *(const float4*)&ws[WS_BVW + 4 * f];
    #pragma unroll
    for (int n = 0; n < 4; ++n) { accK[n] = bK; accQ[n] = bQ; accV[n] = bV; sacc[n] = 0.f; }

    for (int a = 0; a < HD; a += 4) {
        float hf[4][4];
        #pragma unroll
        for (int n = 0; n < 4; ++n) {
            uint2 hu = *(const uint2*)&hs[(nl0 + n) * 36 + (a >> 1)];
            hf[n][0] = blo(hu.x); hf[n][1] = bhi(hu.x);
            hf[n][2] = blo(hu.y); hf[n][3] = bhi(hu.y);
        }
        #pragma unroll
        for (int aa = 0; aa < 4; ++aa) {
            float4 mk = *(const float4*)&ws[WS_MK + (a + aa) * HD + 4 * f];
            float4 mq = *(const float4*)&ws[WS_MQ + (a + aa) * HD + 4 * f];
            float4 mv = *(const float4*)&ws[WS_MVW + (a + aa) * HD + 4 * f];
            float wk = ws[WS_WSK1 + a + aa];
            #pragma unroll
            for (int n = 0; n < 4; ++n) {
                float s1 = hf[n][aa];
                accK[n].x += s1 * mk.x; accK[n].y += s1 * mk.y;
                accK[n].z += s1 * mk.z; accK[n].w += s1 * mk.w;
                accQ[n].x += s1 * mq.x; accQ[n].y += s1 * mq.y;
                accQ[n].z += s1 * mq.z; accQ[n].w += s1 * mq.w;
                accV[n].x += s1 * mv.x; accV[n].y += s1 * mv.y;
                accV[n].z += s1 * mv.z; accV[n].w += s1 * mv.w;
                sacc[n] += s1 * wk;
            }
        }
    }
    #pragma unroll
    for (int n = 0; n < 4; ++n) {
        int node = nbase + nl0 + n;
        if (node < N) {
            unsigned* rec = nodebuf + (size_t)node * 64;
            rec[f] = encq(accK[n]);                       // k u8
            rec[16 + f] = encq(accQ[n]);                  // q u8
            *(uint2*)&rec[32 + 2 * f] = pack4(accV[n]);   // vw bf16
            if (f == 0) score[node] = base + sacc[n];
        }
    }
}

// ---------------------------------------------------------------------------
// Edge: score[dst] += sum_t sigma(k[dst]+q[src])_t * vw[src]_t
// 4 lanes/edge, u8 k/q + bf16 vw, poly sigmoid (no trans), 1 atomic/edge.
// Per edge: 1 sector k + 3 sectors q|vw = 256 B gathered.  (UNCHANGED)
// ---------------------------------------------------------------------------
__global__ __launch_bounds__(256) void gnn_edge(const int* __restrict__ ei,
                                                const uint4* __restrict__ nb,
                                                float* __restrict__ score, int E) {
    int t = blockIdx.x * 256 + threadIdx.x;
    int e = t >> 2;
    if (e >= E) return;
    int f = t & 3;
    int s = ei[e];
    int d = ei[E + e];
    uint4 ku = nb[(size_t)d * 16 + f];           // 16 k-bytes
    uint4 qu = nb[(size_t)s * 16 + 4 + f];       // 16 q-bytes
    uint4 va = nb[(size_t)s * 16 + 8 + 2 * f];   // 8 vw bf16
    uint4 vb = nb[(size_t)s * 16 + 9 + 2 * f];   // 8 vw bf16
    float p = 0.f;
    p = grp4(ku.x, qu.x, va.x, va.y, p);
    p = grp4(ku.y, qu.y, va.z, va.w, p);
    p = grp4(ku.z, qu.z, vb.x, vb.y, p);
    p = grp4(ku.w, qu.w, vb.z, vb.w, p);
    p += __shfl_down(p, 2, 4);
    p += __shfl_down(p, 1, 4);
    if (f == 0) atomicAdd(&score[d], p);
}

// ---------------------------------------------------------------------------
extern "C" void kernel_launch(void* const* d_in, const int* in_sizes, int n_in,
                              void* d_out, int out_size, void* d_ws, size_t ws_size,
                              hipStream_t stream) {
    const float* x    = (const float*)d_in[0];
    const int*   ei   = (const int*)d_in[1];
    const float* W1   = (const float*)d_in[2];
    const float* b1   = (const float*)d_in[3];
    const float* W2   = (const float*)d_in[4];
    const float* b2   = (const float*)d_in[5];
    const float* Wk   = (const float*)d_in[6];
    const float* bk   = (const float*)d_in[7];
    const float* Wq   = (const float*)d_in[8];
    const float* bq   = (const float*)d_in[9];
    const float* Wv   = (const float*)d_in[10];
    const float* bv   = (const float*)d_in[11];
    const float* Wsm  = (const float*)d_in[12];
    const float* bgat = (const float*)d_in[13];
    const float* Wsc  = (const float*)d_in[14];
    const float* bsc  = (const float*)d_in[15];

    int N = in_sizes[0] / FIN;
    int E = in_sizes[1] / 2;

    float* ws    = (float*)d_ws;
    float* recs  = ws + WS_H1;                    // 256 B/node records
    float* score = (float*)d_out;

    int NB = (N + 63) / 64;
    gnn_prep<<<14, 256, 0, stream>>>(W1, W2, b2, Wk, bk, Wq, bq, Wv, bv,
                                     Wsm, Wsc, bgat, bsc, ws);
    gnn_node<<<NB, 256, 0, stream>>>(x, b1, ws, (unsigned*)recs, score, N);
    gnn_edge<<<(E * 4 + 255) / 256, 256, 0, stream>>>(ei, (const uint4*)recs, score, E);
}

// Round 3
// 294.283 us; speedup vs baseline: 1.0764x; 1.0549x over previous
//
#include <hip/hip_runtime.h>

#define HD  64
#define FIN 128

// ---- workspace float offsets ----
#define WS_W1H   0        // [64][128] bf16 hi  (B-operand layout: [col][k])
#define WS_W1L   4096     // [64][128] bf16 lo
#define WS_MALL  8192     // [208][64] bf16: rows 0-63 K, 64-127 Q, 128-191 VW,
                          //   192 skip-vec, 193-207 zero   (26.6 KB)
#define WS_BK    14848    // [64] f32  bk + b2@WkT
#define WS_BQ    14912
#define WS_BVW   14976
#define WS_BASE  15040    // scalar: bsc + b_gate.Wsc + b2.wsk
#define WS_REC   15104    // per-node 256B records: k u8[64] | q u8[64] | vw bf16[64]

// sigmoid quintic on clamped domain x in [-2,2], encoded s = 64*x:
#define C1f  3.9026344e-3f
#define C3f  (-7.67612e-8f)
#define C5f  1.2236660e-12f

typedef __attribute__((ext_vector_type(8))) short short8;
typedef __attribute__((ext_vector_type(4))) float f32x4;

__device__ __forceinline__ unsigned bf16rne(float f) {
    unsigned u = __float_as_uint(f);
    unsigned r = ((u >> 16) & 1u) + 0x7fffu;
    return (u + r) >> 16;
}
__device__ __forceinline__ float blo(unsigned u) { return __uint_as_float(u << 16); }
__device__ __forceinline__ float bhi(unsigned u) { return __uint_as_float(u & 0xffff0000u); }

// 4 features: k,q u8 quads + 4 bf16 vw in (va,vb)
__device__ __forceinline__ float grp4(unsigned ku, unsigned qu, unsigned va,
                                      unsigned vb, float p) {
    #pragma unroll
    for (int i = 0; i < 4; ++i) {
        float kf = (float)((ku >> (8 * i)) & 255u);
        float qf = (float)((qu >> (8 * i)) & 255u);
        unsigned vu = (i < 2) ? va : vb;
        float vf = (i & 1) ? bhi(vu) : blo(vu);
        float xx = kf + qf;
        xx = fminf(fmaxf(xx, 128.f), 384.f);
        float sv = xx - 256.f;
        float z = sv * sv;
        float w = fmaf(z, C5f, C3f);
        w = fmaf(z, w, C1f);
        p = fmaf(vf * sv, w, p);
        p = fmaf(vf, 0.5f, p);
    }
    return p;
}

// ---------------------------------------------------------------------------
// Prep (14 blocks): b0 W1 hi/lo bf16 split; b1-12 LDS-staged folds -> Mall
// bf16 [out][in]; b13 skip fold -> Mall row 192 + zeros + base.
// ---------------------------------------------------------------------------
__global__ void gnn_prep(const float* __restrict__ W1, const float* __restrict__ W2,
                         const float* __restrict__ b2,
                         const float* __restrict__ Wk, const float* __restrict__ bk,
                         const float* __restrict__ Wq, const float* __restrict__ bq,
                         const float* __restrict__ Wv, const float* __restrict__ bv,
                         const float* __restrict__ Wsm, const float* __restrict__ Wsc,
                         const float* __restrict__ bgate, const float* __restrict__ bsc,
                         float* __restrict__ ws) {
    __shared__ float w2s[4096];
    __shared__ float wxsT[65 * 64];    // [c][o], stride 65
    int b = blockIdx.x, t = threadIdx.x;
    unsigned short* w1h  = (unsigned short*)(ws + WS_W1H);
    unsigned short* w1l  = (unsigned short*)(ws + WS_W1L);
    unsigned short* mall = (unsigned short*)(ws + WS_MALL);
    if (b == 0) {                                   // W1 split (native [o][c] layout)
        for (int idx = t; idx < HD * FIN; idx += blockDim.x) {
            float v = W1[idx];
            unsigned u = __float_as_uint(v);
            w1h[idx] = (unsigned short)(u >> 16);             // truncated hi
            float rem = v - __uint_as_float(u & 0xffff0000u);
            w1l[idx] = (unsigned short)bf16rne(rem);          // rne lo
        }
    } else if (b <= 12) {
        int m = (b - 1) >> 2, qtr = (b - 1) & 3;
        const float* Wx = (m == 0) ? Wk : (m == 1) ? Wq : Wv;
        const float* bx = (m == 0) ? bk : (m == 1) ? bq : bv;
        int boff = (m == 0) ? WS_BK : (m == 1) ? WS_BQ : WS_BVW;
        for (int i = t * 4; i < 4096; i += 1024)
            *(float4*)&w2s[i] = *(const float4*)&W2[i];
        for (int idx = t; idx < 4096; idx += 256) {
            int o = idx >> 6, c = idx & 63;
            wxsT[c * 65 + o] = Wx[idx];
        }
        __syncthreads();
        for (int idx = t; idx < 1024; idx += 256) {
            int a = qtr * 16 + (idx >> 6), o = idx & 63;
            float acc = 0.f;
            for (int c = 0; c < HD; ++c) acc += w2s[c * HD + a] * wxsT[c * 65 + o];
            if (m == 2) acc *= Wsc[o];
            mall[(m * 64 + o) * HD + a] = (unsigned short)bf16rne(acc);
        }
        if (qtr == 0 && t < HD) {
            float acc = bx[t];
            for (int c = 0; c < HD; ++c) acc += b2[c] * wxsT[c * 65 + t];
            if (m == 2) acc *= Wsc[t];
            ws[boff + t] = acc;
        }
    } else {                                        // skip-path fold
        __shared__ float wsk[HD];
        if (t < HD) {
            float a = 0.f;
            for (int d = 0; d < HD; ++d) a += Wsm[d * HD + t] * Wsc[d];
            wsk[t] = a;
        }
        __syncthreads();
        if (t < HD) {
            float a = 0.f;
            for (int c = 0; c < HD; ++c) a += W2[c * HD + t] * wsk[c];
            mall[192 * HD + t] = (unsigned short)bf16rne(a);
        }
        for (int idx = t; idx < 15 * HD; idx += 256)     // zero rows 193-207
            mall[193 * HD + idx] = 0;
        if (t == 0) {
            float a = bsc[0];
            for (int d = 0; d < HD; ++d) a += bgate[d] * Wsc[d];
            float acc2 = 0.f;
            __syncthreads();                              // (wsk already visible)
            for (int c = 0; c < HD; ++c) {
                float wk2 = 0.f;
                for (int d = 0; d < HD; ++d) wk2 += Wsm[d * HD + c] * Wsc[d];
                acc2 += b2[c] * wk2;
            }
            ws[WS_BASE] = a + acc2;
        }
    }
}

// ---------------------------------------------------------------------------
// MFMA node kernel. 64 nodes/block, 4 waves (16 nodes each, fully independent
// M-stripes). Phase 1: h = relu(x@W1T+b1) via split-bf16 (3 MFMA passes, fp32-
// accurate). Phase 2: [K|Q|VW|skip] = h @ Mall (13 N-tiles). Weights stream
// from global (L1-resident, 16B/lane/MFMA). LDS: XH/XL 32KB swizzled
// (byte ^= (row&7)<<4), aliased for H + u8/bf16 epilogue staging.
// ---------------------------------------------------------------------------
__global__ __launch_bounds__(256, 3) void gnn_node(const float* __restrict__ x,
                                                   const float* __restrict__ b1,
                                                   const float* __restrict__ ws,
                                                   unsigned* __restrict__ nodebuf,
                                                   float* __restrict__ score, int N) {
    __shared__ __align__(16) char smem[32768];
    // phase1: XH bytes [0,16384) [64][128]bf16 swz; XL [16384,32768)
    // phase2: H bytes [0,8192) [64][64]bf16 swz
    // epilogue: Ku8 @16384 [64][64]u8; Qu8 @20480; VW @24576 [64][64]bf16
    char* XHb = smem;
    char* XLb = smem + 16384;

    int tid = threadIdx.x;
    int l = tid & 63, w = tid >> 6;
    int nbase = blockIdx.x * 64;

    // ---- stage x -> XH/XL (wave-aligned rows, split bf16, swizzled) ----
    #pragma unroll
    for (int it = 0; it < 8; ++it) {
        int idx = it * 64 + l;                    // 0..511
        int nl = 16 * w + (idx >> 5);             // this wave's rows
        int c4 = idx & 31;
        int node = min(nbase + nl, N - 1);
        float4 v = ((const float4*)x)[(size_t)node * 32 + c4];
        unsigned u0 = __float_as_uint(v.x), u1 = __float_as_uint(v.y);
        unsigned u2 = __float_as_uint(v.z), u3 = __float_as_uint(v.w);
        uint2 hx, lx;
        hx.x = (u0 >> 16) | (u1 & 0xffff0000u);
        hx.y = (u2 >> 16) | (u3 & 0xffff0000u);
        float r0 = v.x - __uint_as_float(u0 & 0xffff0000u);
        float r1 = v.y - __uint_as_float(u1 & 0xffff0000u);
        float r2 = v.z - __uint_as_float(u2 & 0xffff0000u);
        float r3 = v.w - __uint_as_float(u3 & 0xffff0000u);
        lx.x = bf16rne(r0) | (bf16rne(r1) << 16);
        lx.y = bf16rne(r2) | (bf16rne(r3) << 16);
        int bo = (nl * 256 + c4 * 8) ^ ((nl & 7) << 4);
        *(uint2*)(XHb + bo) = hx;
        *(uint2*)(XLb + bo) = lx;
    }
    __syncthreads();

    int rl = l & 15, kb = l >> 4;
    int rowA = 16 * w + rl;                       // A-frag row for this lane
    int swzA = (rowA & 7) << 4;

    // ---- phase 1: 3-way split bf16 MFMA, K=128 ----
    const unsigned short* w1h = (const unsigned short*)(ws + WS_W1H);
    const unsigned short* w1l = (const unsigned short*)(ws + WS_W1L);
    f32x4 acc1[4];
    #pragma unroll
    for (int t = 0; t < 4; ++t) {
        float bv = b1[t * 16 + rl];
        acc1[t] = (f32x4){bv, bv, bv, bv};
    }
    #pragma unroll
    for (int s = 0; s < 4; ++s) {
        int abyte = (rowA * 256 + s * 64 + kb * 16) ^ swzA;
        short8 ah = *(const short8*)(XHb + abyte);
        short8 al = *(const short8*)(XLb + abyte);
        int koff = s * 32 + kb * 8;
        #pragma unroll
        for (int t = 0; t < 4; ++t) {
            int col = t * 16 + rl;
            short8 bh = *(const short8*)&w1h[col * FIN + koff];
            short8 bl = *(const short8*)&w1l[col * FIN + koff];
            acc1[t] = __builtin_amdgcn_mfma_f32_16x16x32_bf16(ah, bh, acc1[t], 0, 0, 0);
            acc1[t] = __builtin_amdgcn_mfma_f32_16x16x32_bf16(al, bh, acc1[t], 0, 0, 0);
            acc1[t] = __builtin_amdgcn_mfma_f32_16x16x32_bf16(ah, bl, acc1[t], 0, 0, 0);
        }
    }
    __syncthreads();                              // all XH/XL reads done (H aliases XH)

    // ---- relu + bf16, write H [64][64] swizzled ----
    int r0w = (l >> 4) * 4;                       // C-frag row base
    #pragma unroll
    for (int t = 0; t < 4; ++t) {
        int col = t * 16 + rl;
        #pragma unroll
        for (int r = 0; r < 4; ++r) {
            int row = 16 * w + r0w + r;
            float v = fmaxf(acc1[t][r], 0.f);
            int hb = (row * 128 + col * 2) ^ ((row & 7) << 4);
            *(unsigned short*)(smem + hb) = (unsigned short)bf16rne(v);
        }
    }
    __syncthreads();                              // H complete

    // ---- phase 2: [K|Q|VW|skip] = H @ Mall, K=64, 13 N-tiles ----
    const unsigned short* mall = (const unsigned short*)(ws + WS_MALL);
    const float* bK = ws + WS_BK;
    const float* bQ = ws + WS_BQ;
    const float* bV = ws + WS_BVW;
    float base = ws[WS_BASE];
    f32x4 acc2[13];
    #pragma unroll
    for (int t = 0; t < 4; ++t) {
        float v = bK[t * 16 + rl];
        acc2[t] = (f32x4){v, v, v, v};
    }
    #pragma unroll
    for (int t = 0; t < 4; ++t) {
        float v = bQ[t * 16 + rl];
        acc2[4 + t] = (f32x4){v, v, v, v};
    }
    #pragma unroll
    for (int t = 0; t < 4; ++t) {
        float v = bV[t * 16 + rl];
        acc2[8 + t] = (f32x4){v, v, v, v};
    }
    acc2[12] = (f32x4){0.f, 0.f, 0.f, 0.f};

    #pragma unroll
    for (int s = 0; s < 2; ++s) {
        int abyte = (rowA * 128 + (s * 32 + kb * 8) * 2) ^ swzA;
        short8 a = *(const short8*)(smem + abyte);
        int koff = s * 32 + kb * 8;
        #pragma unroll
        for (int t = 0; t < 13; ++t) {
            short8 b = *(const short8*)&mall[(t * 16 + rl) * HD + koff];
            acc2[t] = __builtin_amdgcn_mfma_f32_16x16x32_bf16(a, b, acc2[t], 0, 0, 0);
        }
    }

    // ---- epilogue: quantize to LDS staging (per-wave rows), then coalesced copy
    char* Ku = smem + 16384;
    char* Qu = smem + 20480;
    char* VW = smem + 24576;
    #pragma unroll
    for (int t = 0; t < 4; ++t) {
        int col = t * 16 + rl;
        #pragma unroll
        for (int r = 0; r < 4; ++r) {
            int row = 16 * w + r0w + r;
            int ek = min(max(__float2int_rn(fmaf(acc2[t][r],     64.f, 128.f)), 0), 255);
            int eq = min(max(__float2int_rn(fmaf(acc2[4 + t][r], 64.f, 128.f)), 0), 255);
            Ku[row * 64 + col] = (char)ek;
            Qu[row * 64 + col] = (char)eq;
            *(unsigned short*)(VW + row * 128 + col * 2) =
                (unsigned short)bf16rne(acc2[8 + t][r]);
        }
    }
    if (rl == 0) {                                // skip-tile col 0 = score
        #pragma unroll
        for (int r = 0; r < 4; ++r) {
            int node = nbase + 16 * w + r0w + r;
            if (node < N) score[node] = base + acc2[12][r];
        }
    }
    __syncthreads();

    uint4* recs = (uint4*)nodebuf;
    #pragma unroll
    for (int it = 0; it < 4; ++it) {
        int c = it * 256 + tid;                   // 1024 chunks of 16B
        int n = c >> 4, p = c & 15;
        uint4 v;
        if (p < 4)      v = *(const uint4*)(Ku + n * 64 + p * 16);
        else if (p < 8) v = *(const uint4*)(Qu + n * 64 + (p - 4) * 16);
        else            v = *(const uint4*)(VW + n * 128 + (p - 8) * 16);
        int node = nbase + n;
        if (node < N) recs[(size_t)node * 16 + p] = v;
    }
}

// ---------------------------------------------------------------------------
// Edge: score[dst] += sum_t sigma(k[dst]+q[src])_t * vw[src]_t   (UNCHANGED)
// ---------------------------------------------------------------------------
__global__ __launch_bounds__(256) void gnn_edge(const int* __restrict__ ei,
                                                const uint4* __restrict__ nb,
                                                float* __restrict__ score, int E) {
    int t = blockIdx.x * 256 + threadIdx.x;
    int e = t >> 2;
    if (e >= E) return;
    int f = t & 3;
    int s = ei[e];
    int d = ei[E + e];
    uint4 ku = nb[(size_t)d * 16 + f];
    uint4 qu = nb[(size_t)s * 16 + 4 + f];
    uint4 va = nb[(size_t)s * 16 + 8 + 2 * f];
    uint4 vb = nb[(size_t)s * 16 + 9 + 2 * f];
    float p = 0.f;
    p = grp4(ku.x, qu.x, va.x, va.y, p);
    p = grp4(ku.y, qu.y, va.z, va.w, p);
    p = grp4(ku.z, qu.z, vb.x, vb.y, p);
    p = grp4(ku.w, qu.w, vb.z, vb.w, p);
    p += __shfl_down(p, 2, 4);
    p += __shfl_down(p, 1, 4);
    if (f == 0) atomicAdd(&score[d], p);
}

// ---------------------------------------------------------------------------
extern "C" void kernel_launch(void* const* d_in, const int* in_sizes, int n_in,
                              void* d_out, int out_size, void* d_ws, size_t ws_size,
                              hipStream_t stream) {
    const float* x    = (const float*)d_in[0];
    const int*   ei   = (const int*)d_in[1];
    const float* W1   = (const float*)d_in[2];
    const float* b1   = (const float*)d_in[3];
    const float* W2   = (const float*)d_in[4];
    const float* b2   = (const float*)d_in[5];
    const float* Wk   = (const float*)d_in[6];
    const float* bk   = (const float*)d_in[7];
    const float* Wq   = (const float*)d_in[8];
    const float* bq   = (const float*)d_in[9];
    const float* Wv   = (const float*)d_in[10];
    const float* bv   = (const float*)d_in[11];
    const float* Wsm  = (const float*)d_in[12];
    const float* bgat = (const float*)d_in[13];
    const float* Wsc  = (const float*)d_in[14];
    const float* bsc  = (const float*)d_in[15];

    int N = in_sizes[0] / FIN;
    int E = in_sizes[1] / 2;

    float* ws    = (float*)d_ws;
    float* recs  = ws + WS_REC;
    float* score = (float*)d_out;

    int NB = (N + 63) / 64;
    gnn_prep<<<14, 256, 0, stream>>>(W1, W2, b2, Wk, bk, Wq, bq, Wv, bv,
                                     Wsm, Wsc, bgat, bsc, ws);
    gnn_node<<<NB, 256, 0, stream>>>(x, b1, ws, (unsigned*)recs, score, N);
    gnn_edge<<<(E * 4 + 255) / 256, 256, 0, stream>>>(ei, (const uint4*)recs, score, E);
}